// Round 20
// baseline (220.449 us; speedup 1.0000x reference)
//
#include <hip/hip_runtime.h>
#include <hip/hip_bf16.h>
#include <math.h>

#define L_DIM 1024
#define DM 1024
#define DI 2048
#define NS 64

typedef __attribute__((ext_vector_type(8))) short short8;
typedef __attribute__((ext_vector_type(4))) float f32x4;

__device__ __forceinline__ ushort bf16u(float f)
{
    unsigned u = __float_as_uint(f);
    unsigned r = (u + 0x7fffu + ((u >> 16) & 1u)) >> 16;
    return (ushort)r;
}
__device__ __forceinline__ float bf2f(ushort u)
{
    return __uint_as_float((unsigned)u << 16);
}

__device__ __forceinline__ void gld16(const ushort* g, const ushort* l)
{
    __builtin_amdgcn_global_load_lds(
        (const __attribute__((address_space(1))) unsigned int*)g,
        (__attribute__((address_space(3))) unsigned int*)l, 16, 0, 0);
}

// -------- fused RMSNorm + bf16 cast ------------------------------------------
__global__ __launch_bounds__(256) void k_rms_xn(const float* __restrict__ x,
    const float* __restrict__ nw, ushort* __restrict__ d)
{
    int row = blockIdx.x;
    const float* xp = x + (size_t)row * DM;
    float4 v = ((const float4*)xp)[threadIdx.x];
    float ss = v.x*v.x + v.y*v.y + v.z*v.z + v.w*v.w;
    #pragma unroll
    for (int m = 32; m; m >>= 1) ss += __shfl_xor(ss, m, 64);
    __shared__ float red[4];
    if ((threadIdx.x & 63) == 0) red[threadIdx.x >> 6] = ss;
    __syncthreads();
    float tot = red[0] + red[1] + red[2] + red[3];
    float ri = rsqrtf(tot * (1.0f / DM) + 1e-6f);
    float4 wv = ((const float4*)nw)[threadIdx.x];
    ((ushort4*)(d + (size_t)row * DM))[threadIdx.x] =
        make_ushort4(bf16u(v.x*ri*wv.x), bf16u(v.y*ri*wv.y),
                     bf16u(v.z*ri*wv.z), bf16u(v.w*ri*wv.w));
}

// ---------------- all weight casts in ONE dispatch ---------------------------
__device__ __forceinline__ void cast8(const float* __restrict__ s,
                                      ushort* __restrict__ d, int i)
{
    float4 a = ((const float4*)s)[2*i], b = ((const float4*)s)[2*i+1];
    ((ushort4*)d)[2*i]   = make_ushort4(bf16u(a.x), bf16u(a.y), bf16u(a.z), bf16u(a.w));
    ((ushort4*)d)[2*i+1] = make_ushort4(bf16u(b.x), bf16u(b.y), bf16u(b.z), bf16u(b.w));
}
__global__ __launch_bounds__(256) void k_castw(
    const float* __restrict__ s0, ushort* __restrict__ d0,
    const float* __restrict__ s1, ushort* __restrict__ d1,
    const float* __restrict__ s2, ushort* __restrict__ d2,
    const float* __restrict__ s3, ushort* __restrict__ d3)
{
    int i = blockIdx.x * 256 + threadIdx.x;
    if (i < 524288)       cast8(s0, d0, i);
    else if (i < 1048576) cast8(s1, d1, i - 524288);
    else if (i < 1064960) cast8(s2, d2, i - 1048576);
    else                  cast8(s3, d3, i - 1064960);
}

// ------- MFMA NT GEMM, BM templated (128 or 64) x 128, BK=64, swizzled -------
// MODE 0: bf16 out (C0b, row-major ldc).
// MODE 1: non-XP -> softplus dt TRANSPOSED bf16 into C0b[b][col][t];
//         XP -> f32 B TRANSPOSED into C1[b][n][t] (BssT).
// MODE 2: f32 out + skip (C0).
template<int MODE, int BM>
__global__ __launch_bounds__(256) void k_mfma(
    const ushort* __restrict__ Abf, const ushort* __restrict__ Bbf0,
    const ushort* __restrict__ Bbf1, float* __restrict__ C0,
    ushort* __restrict__ C0b, float* __restrict__ C1,
    const float* __restrict__ bias, const float* __restrict__ skip,
    int Kdim, int ldc)
{
    constexpr int NI = (BM == 128) ? 4 : 2;
    constexpr int SA = BM / 32;
    __shared__ __align__(16) ushort As[BM*64];
    __shared__ __align__(16) ushort Bs[128*64];
    const int t = threadIdx.x, w = t >> 6, lane = t & 63;
    const int nwg = gridDim.x * gridDim.y;
    const int orig = blockIdx.y * gridDim.x + blockIdx.x;
    const int swz = (orig & 7) * (nwg >> 3) + (orig >> 3);
    const int nt = swz % gridDim.x, mt = swz / gridDim.x;
    const int mBase = mt * BM, nBase = nt * 128;
    const bool isXP = (MODE == 1) && (nt == 16);
    const ushort* __restrict__ Bbf = isXP ? Bbf1 : Bbf0;
    const int wr = (BM == 128) ? (w >> 1) * 64 : 0;
    const int wc = (BM == 128) ? (w & 1) * 64 : w * 32;
    const int sR = lane >> 3;
    const int sK = ((lane & 7) ^ sR) * 8;

    f32x4 acc[4][NI];
    #pragma unroll
    for (int i = 0; i < 4; ++i)
        #pragma unroll
        for (int j = 0; j < NI; ++j)
            acc[i][j] = (f32x4){0.f, 0.f, 0.f, 0.f};

    for (int kt = 0; kt < Kdim; kt += 64) {
        #pragma unroll
        for (int s = 0; s < SA; ++s) {
            int tr = w*8 + s*32 + sR;
            gld16(Abf + (size_t)(mBase + tr) * Kdim + kt + sK,
                  As + (w*8 + s*32) * 64);
        }
        #pragma unroll
        for (int s = 0; s < 4; ++s) {
            int tr = w*8 + s*32 + sR;
            int gr = isXP ? (tr < 63 ? tr : 63) : (nBase + tr);
            gld16(Bbf + (size_t)gr * Kdim + kt + sK,
                  Bs + (w*8 + s*32) * 64);
        }
        __syncthreads();
        #pragma unroll
        for (int kk = 0; kk < 2; ++kk) {
            short8 af[4], bfr[NI];
            #pragma unroll
            for (int f = 0; f < 4; ++f) {
                int ra = wr + f*16 + (lane & 15);
                int ca = (kk*4 + (lane >> 4)) ^ (ra & 7);
                af[f] = *(const short8*)(As + ra*64 + ca*8);
            }
            #pragma unroll
            for (int f = 0; f < NI; ++f) {
                int rb2 = wc + f*16 + (lane & 15);
                int cb2 = (kk*4 + (lane >> 4)) ^ (rb2 & 7);
                bfr[f] = *(const short8*)(Bs + rb2*64 + cb2*8);
            }
            #pragma unroll
            for (int mi = 0; mi < 4; ++mi)
                #pragma unroll
                for (int ni = 0; ni < NI; ++ni)
                    acc[mi][ni] = __builtin_amdgcn_mfma_f32_16x16x32_bf16(
                        af[mi], bfr[ni], acc[mi][ni], 0, 0, 0);
        }
        __syncthreads();
    }

    const int rb = (lane >> 4) * 4, cbl = lane & 15;
    #pragma unroll
    for (int mi = 0; mi < 4; ++mi) {
        #pragma unroll
        for (int ni = 0; ni < NI; ++ni) {
            int ltcol = wc + ni*16 + cbl;
            int col = nBase + ltcol;
            int row0 = mBase + wr + mi*16 + rb;
            if constexpr (MODE == 0) {
                #pragma unroll
                for (int j = 0; j < 4; ++j)
                    C0b[(size_t)(row0+j) * ldc + col] = bf16u(acc[mi][ni][j]);
            } else if constexpr (MODE == 1) {
                int b_ = row0 >> 10, trow = row0 & 1023;
                if (isXP) {
                    if (ltcol < NS) {
                        f32x4 v = acc[mi][ni];
                        *(f32x4*)(C1 + ((size_t)b_ * NS + ltcol) * L_DIM + trow) = v;
                    }
                } else {
                    ushort o[4];
                    #pragma unroll
                    for (int j = 0; j < 4; ++j) {
                        float z = acc[mi][ni][j] + bias[col];
                        float sp = (z > 20.f) ? z : logf(1.f + expf(z));
                        o[j] = bf16u(sp);
                    }
                    *(ushort4*)(C0b + ((size_t)b_ * DI + col) * L_DIM + trow) =
                        *(ushort4*)o;
                }
            } else {
                #pragma unroll
                for (int j = 0; j < 4; ++j)
                    C0[(size_t)(row0+j) * ldc + col] =
                        acc[mi][ni][j] + skip[(size_t)(row0+j) * ldc + col];
            }
        }
    }
}

// ----- fused causal conv1d(K=4)+SiLU -> xc row-major AND xct transposed ------
__global__ __launch_bounds__(256) void k_convt(const ushort* __restrict__ xrb,
    const float* __restrict__ cw, const float* __restrict__ cb,
    ushort* __restrict__ xcb, ushort* __restrict__ xct)
{
    __shared__ __align__(16) ushort in[68][72];   // rows 0..66 = t0-3..t0+63
    __shared__ __align__(16) ushort ot[64][72];   // conv output, swizzled
    const int dt_ = blockIdx.x;                   // d tile (32)
    const int tt_ = blockIdx.y;                   // t tile (16)
    const int b   = blockIdx.z;
    const int d0 = dt_ * 64, t0 = tt_ * 64;
    const int tx = threadIdx.x & 7, ty = threadIdx.x >> 3;   // 8 x 32
    const ushort* src = xrb + (size_t)b * L_DIM * (2*DI) + d0;

    for (int r = threadIdx.x >> 3; r < 67; r += 32) {
        int tg = t0 - 3 + r;
        short8 v;
        if (tg < 0) {
            v = (short8){0,0,0,0,0,0,0,0};
        } else {
            v = *(const short8*)(src + (size_t)tg * (2*DI) + tx*8);
        }
        *(short8*)&in[r][tx*8] = v;
    }
    float wj[4][8];
    float bias8[8];
    #pragma unroll
    for (int j = 0; j < 8; ++j) {
        int dg = d0 + tx*8 + j;
        bias8[j] = cb[dg];
        #pragma unroll
        for (int c = 0; c < 4; ++c) wj[c][j] = cw[(size_t)dg * 4 + c];
    }
    __syncthreads();

    #pragma unroll
    for (int p = 0; p < 2; ++p) {
        int r = ty + p*32;                        // local t index
        short8 x0 = *(const short8*)&in[r + 0][tx*8];
        short8 x1 = *(const short8*)&in[r + 1][tx*8];
        short8 x2 = *(const short8*)&in[r + 2][tx*8];
        short8 x3 = *(const short8*)&in[r + 3][tx*8];
        ushort o[8];
        #pragma unroll
        for (int j = 0; j < 8; ++j) {
            float a = bias8[j];
            a = fmaf(wj[0][j], bf2f(((const ushort*)&x0)[j]), a);
            a = fmaf(wj[1][j], bf2f(((const ushort*)&x1)[j]), a);
            a = fmaf(wj[2][j], bf2f(((const ushort*)&x2)[j]), a);
            a = fmaf(wj[3][j], bf2f(((const ushort*)&x3)[j]), a);
            a = a / (1.f + expf(-a));
            o[j] = bf16u(a);
        }
        *(short8*)(xcb + ((size_t)(b * L_DIM + t0 + r) * DI) + d0 + tx*8) =
            *(short8*)o;
        int g = tx ^ ((r >> 3) & 7);
        *(short8*)&ot[r][g*8] = *(short8*)o;
    }
    __syncthreads();
    #pragma unroll
    for (int p = 0; p < 2; ++p) {
        int crow = ty + p*32;                     // d index within tile
        ushort o[8];
        #pragma unroll
        for (int j = 0; j < 8; ++j)
            o[j] = ot[tx*8 + j][(((crow >> 3) ^ tx) << 3) + (crow & 7)];
        *(short8*)(xct + ((size_t)b * DI + d0 + crow) * L_DIM + t0 + tx*8) =
            *(short8*)o;
    }
}

// ------ back-transpose yt[b][d][t](bf16) -> y_bf[b*t][d], fused silu gate ----
__global__ __launch_bounds__(256) void k_trg(const ushort* __restrict__ yt,
    const ushort* __restrict__ xrb, ushort* __restrict__ ybf)
{
    __shared__ __align__(16) ushort tile[64][72];
    const int r0 = blockIdx.y * 64, c0 = blockIdx.x * 64;  // r: d, c: t
    const int z = blockIdx.z;
    const ushort* s = yt + (size_t)z * DI * L_DIM;
    const int tx = threadIdx.x & 7, ty = threadIdx.x >> 3;
    #pragma unroll
    for (int p = 0; p < 2; ++p) {
        int r = ty + p*32;
        short8 v = *(const short8*)(s + (size_t)(r0 + r) * L_DIM + c0 + tx*8);
        int g = tx ^ ((r >> 3) & 7);
        *(short8*)&tile[r][g*8] = v;
    }
    __syncthreads();
    #pragma unroll
    for (int p = 0; p < 2; ++p) {
        int crow = ty + p*32;                 // t index within tile
        int row = z * L_DIM + c0 + crow;      // global (b*t) row
        ushort4 gu0 = *(const ushort4*)(xrb + (size_t)row * (2*DI) + DI + r0 + tx*8);
        ushort4 gu1 = *(const ushort4*)(xrb + (size_t)row * (2*DI) + DI + r0 + tx*8 + 4);
        ushort o[8];
        #pragma unroll
        for (int j = 0; j < 8; ++j) {
            float yv = bf2f(tile[tx*8 + j][(((crow >> 3) ^ tx) << 3) + (crow & 7)]);
            float g = bf2f(j < 4 ? ((const ushort*)&gu0)[j] : ((const ushort*)&gu1)[j-4]);
            o[j] = bf16u(yv * g / (1.f + expf(-g)));
        }
        *(short8*)(ybf + (size_t)row * DI + r0 + tx*8) = *(short8*)o;
    }
}

__device__ __forceinline__ float exp2_fast(float x)
{
    float r;
    asm("v_exp_f32 %0, %1" : "=v"(r) : "v"(x));
    return r;
}

// -------- selective scan v12: register-prefetch next chunk under compute -----
// Loads for chunk c+1 (B 16 f32, dt, xc) issue BEFORE chunk c's compute loop;
// their ~600cy latency hides under the 64-step compute. LDS write of chunk c+1
// happens after the next barrier.
__global__ __launch_bounds__(256) void k_scan12(const ushort* __restrict__ dtt,
    const ushort* __restrict__ xct, const float* __restrict__ BssT,
    const float* __restrict__ A_log, const float* __restrict__ Dp,
    ushort* __restrict__ yt)
{
    __shared__ __align__(16) float BshT[64][68];
    __shared__ __align__(16) float Psh[4][64][8];
    __shared__ __align__(16) float Dsh[4][64];
    __shared__ __align__(16) float Xsh[4][64];
    const int lane = threadIdx.x & 63;
    const int widx = threadIdx.x >> 6;
    const int b = blockIdx.x >> 9;
    const int d = (blockIdx.x & 511) * 4 + widx;
    const float aL2 = -expf(A_log[(size_t)d * NS + lane]) * 1.44269504f;
    const float Dv = Dp[d];
    const ushort* dtp = dtt + ((size_t)b * DI + d) * L_DIM;
    const ushort* xcp = xct + ((size_t)b * DI + d) * L_DIM;
    const float* BpT = BssT + ((size_t)b * NS + lane) * L_DIM;
    ushort* yp = yt + ((size_t)b * DI + d) * L_DIM;
    const int pg = lane >> 3;
    const bool pwrite = (lane & 7) == 7;
    float h = 0.f;

    // preload chunk 0 into registers
    const float* bsrc0 = BpT + widx*16;
    float4 b0 = *(const float4*)(bsrc0);
    float4 b1 = *(const float4*)(bsrc0 + 4);
    float4 b2 = *(const float4*)(bsrc0 + 8);
    float4 b3 = *(const float4*)(bsrc0 + 12);
    float dt_v = bf2f(dtp[lane]);
    float xc_v = bf2f(xcp[lane]);

    for (int t0 = 0; t0 < L_DIM; t0 += 64) {
        __syncthreads();                       // prev compute's LDS reads done
        *(float4*)&BshT[lane][widx*16]      = b0;
        *(float4*)&BshT[lane][widx*16 + 4]  = b1;
        *(float4*)&BshT[lane][widx*16 + 8]  = b2;
        *(float4*)&BshT[lane][widx*16 + 12] = b3;
        Dsh[widx][lane] = dt_v;
        Xsh[widx][lane] = xc_v;
        float xc_cur = xc_v;                   // current chunk's x for epilogue
        __syncthreads();
        if (t0 + 64 < L_DIM) {                 // prefetch next chunk -> regs;
            const float* bsrc = BpT + t0 + 64 + widx*16;   // latency hides
            b0 = *(const float4*)(bsrc);                   // under compute
            b1 = *(const float4*)(bsrc + 4);
            b2 = *(const float4*)(bsrc + 8);
            b3 = *(const float4*)(bsrc + 12);
            dt_v = bf2f(dtp[t0 + 64 + lane]);
            xc_v = bf2f(xcp[t0 + 64 + lane]);
        }
        #pragma unroll
        for (int q = 0; q < 64; q += 4) {
            float4 dt4 = *(const float4*)&Dsh[widx][q];
            float4 xc4 = *(const float4*)&Xsh[widx][q];
            float4 Bq  = *(const float4*)&BshT[lane][q];
            float s0, s1, s2, s3;
            {
                float p, ad;
                p  = xc4.x * Bq.x;
                ad = exp2_fast(aL2 * dt4.x);
                h = fmaf(ad, h, p); s0 = h;
                p  = xc4.y * Bq.y;
                ad = exp2_fast(aL2 * dt4.y);
                h = fmaf(ad, h, p); s1 = h;
                p  = xc4.z * Bq.z;
                ad = exp2_fast(aL2 * dt4.z);
                h = fmaf(ad, h, p); s2 = h;
                p  = xc4.w * Bq.w;
                ad = exp2_fast(aL2 * dt4.w);
                h = fmaf(ad, h, p); s3 = h;
            }
            asm("v_add_f32_dpp %0, %0, %0 row_shr:1 row_mask:0xf bank_mask:0xf\n\t"
                "v_add_f32_dpp %1, %1, %1 row_shr:1 row_mask:0xf bank_mask:0xf\n\t"
                "v_add_f32_dpp %2, %2, %2 row_shr:1 row_mask:0xf bank_mask:0xf\n\t"
                "v_add_f32_dpp %3, %3, %3 row_shr:1 row_mask:0xf bank_mask:0xf\n\t"
                "v_add_f32_dpp %0, %0, %0 row_shr:2 row_mask:0xf bank_mask:0xf\n\t"
                "v_add_f32_dpp %1, %1, %1 row_shr:2 row_mask:0xf bank_mask:0xf\n\t"
                "v_add_f32_dpp %2, %2, %2 row_shr:2 row_mask:0xf bank_mask:0xf\n\t"
                "v_add_f32_dpp %3, %3, %3 row_shr:2 row_mask:0xf bank_mask:0xf\n\t"
                "v_add_f32_dpp %0, %0, %0 row_shr:4 row_mask:0xf bank_mask:0xf\n\t"
                "v_add_f32_dpp %1, %1, %1 row_shr:4 row_mask:0xf bank_mask:0xf\n\t"
                "v_add_f32_dpp %2, %2, %2 row_shr:4 row_mask:0xf bank_mask:0xf\n\t"
                "v_add_f32_dpp %3, %3, %3 row_shr:4 row_mask:0xf bank_mask:0xf"
                : "+v"(s0), "+v"(s1), "+v"(s2), "+v"(s3));
            if (pwrite) {
                Psh[widx][q+0][pg] = s0;
                Psh[widx][q+1][pg] = s1;
                Psh[widx][q+2][pg] = s2;
                Psh[widx][q+3][pg] = s3;
            }
        }
        asm volatile("s_waitcnt lgkmcnt(0)" ::: "memory");
        __builtin_amdgcn_sched_barrier(0);
        float4 p0 = *(const float4*)&Psh[widx][lane][0];
        float4 p1 = *(const float4*)&Psh[widx][lane][4];
        float sum = ((p0.x + p0.y) + (p0.z + p0.w))
                  + ((p1.x + p1.y) + (p1.z + p1.w));
        yp[t0 + lane] = bf16u(fmaf(Dv, xc_cur, sum));
    }
}

extern "C" void kernel_launch(void* const* d_in, const int* in_sizes, int n_in,
                              void* d_out, int out_size, void* d_ws, size_t ws_size,
                              hipStream_t stream)
{
    const float* x        = (const float*)d_in[0];
    const float* norm_w   = (const float*)d_in[1];
    const float* in_projw = (const float*)d_in[2];
    const float* conv_w   = (const float*)d_in[3];
    const float* conv_b   = (const float*)d_in[4];
    const float* x_projw  = (const float*)d_in[5];
    const float* dt_w     = (const float*)d_in[6];
    const float* dt_b     = (const float*)d_in[7];
    const float* A_log    = (const float*)d_in[8];
    const float* D_param  = (const float*)d_in[9];
    const float* out_projw= (const float*)d_in[10];
    float* out = (float*)d_out;

    ushort* wsu = (ushort*)d_ws;
    ushort* xr_bf  = wsu;                                   // 8M u16
    ushort* xc_bf  = xr_bf + (size_t)8*1024*1024;           // 4M u16
    ushort* dtb_bf = xc_bf + (size_t)4*1024*1024;           // 4M u16 (yt alias)
    ushort* dtt_bf = dtb_bf + (size_t)4*1024*1024;          // 4M u16
    ushort* xct_bf = dtt_bf + (size_t)4*1024*1024;          // 4M u16
    ushort* xn_bf  = xct_bf + (size_t)4*1024*1024;          // 2M u16
    ushort* xpw_bf = xn_bf + (size_t)2*1024*1024;           // 128K u16
    ushort* opw_bf = xpw_bf + 131072;                       // 2M u16
    float*  BssT   = (float*)(opw_bf + (size_t)2*1024*1024); // 128K f32 [b][n][t]
    ushort* dtw_bf = (ushort*)(BssT + 131072);              // fresh 4M u16
    // aliases into dead regions:
    ushort* inpw_bf = dtt_bf;     // consumed by GEMM0, before GEMM1 writes dtt
    ushort* y_bf    = xc_bf;      // xc dead after GEMM1 (xct is separate now)
    ushort* yt_bf   = dtb_bf;     // scratch for scan output

    k_castw<<<5184, 256, 0, stream>>>(in_projw, inpw_bf, dt_w, dtw_bf,
                                      x_projw + (size_t)64*2048, xpw_bf,
                                      out_projw, opw_bf);
    k_rms_xn<<<2048, 256, 0, stream>>>(x, norm_w, xn_bf);
    k_mfma<0,128><<<dim3(32, 16), 256, 0, stream>>>(xn_bf, inpw_bf, nullptr,
                                                nullptr, xr_bf, nullptr,
                                                nullptr, nullptr, 1024, 4096);
    k_convt<<<dim3(32, 16, 2), 256, 0, stream>>>(xr_bf, conv_w, conv_b,
                                                 xc_bf, xct_bf);
    k_mfma<1,128><<<dim3(17, 16), 256, 0, stream>>>(xc_bf, dtw_bf, xpw_bf,
                                                nullptr, dtt_bf, BssT,
                                                dt_b, nullptr, 2048, 2048);
    k_scan12<<<1024, 256, 0, stream>>>(dtt_bf, xct_bf, BssT, A_log, D_param, yt_bf);
    k_trg<<<dim3(16, 32, 2), 256, 0, stream>>>(yt_bf, xr_bf, y_bf);
    k_mfma<2,64><<<dim3(8, 32), 256, 0, stream>>>(y_bf, opw_bf, nullptr,
                                               out, nullptr, nullptr,
                                               nullptr, x, 2048, 1024);
}

// Round 22
// 219.927 us; speedup vs baseline: 1.0024x; 1.0024x over previous
//
#include <hip/hip_runtime.h>
#include <hip/hip_bf16.h>
#include <math.h>

#define L_DIM 1024
#define DM 1024
#define DI 2048
#define NS 64

typedef __attribute__((ext_vector_type(8))) short short8;
typedef __attribute__((ext_vector_type(4))) float f32x4;

__device__ __forceinline__ ushort bf16u(float f)
{
    unsigned u = __float_as_uint(f);
    unsigned r = (u + 0x7fffu + ((u >> 16) & 1u)) >> 16;
    return (ushort)r;
}
__device__ __forceinline__ float bf2f(ushort u)
{
    return __uint_as_float((unsigned)u << 16);
}

__device__ __forceinline__ void gld16(const ushort* g, const ushort* l)
{
    __builtin_amdgcn_global_load_lds(
        (const __attribute__((address_space(1))) unsigned int*)g,
        (__attribute__((address_space(3))) unsigned int*)l, 16, 0, 0);
}

// -------- fused RMSNorm + bf16 cast ------------------------------------------
__global__ __launch_bounds__(256) void k_rms_xn(const float* __restrict__ x,
    const float* __restrict__ nw, ushort* __restrict__ d)
{
    int row = blockIdx.x;
    const float* xp = x + (size_t)row * DM;
    float4 v = ((const float4*)xp)[threadIdx.x];
    float ss = v.x*v.x + v.y*v.y + v.z*v.z + v.w*v.w;
    #pragma unroll
    for (int m = 32; m; m >>= 1) ss += __shfl_xor(ss, m, 64);
    __shared__ float red[4];
    if ((threadIdx.x & 63) == 0) red[threadIdx.x >> 6] = ss;
    __syncthreads();
    float tot = red[0] + red[1] + red[2] + red[3];
    float ri = rsqrtf(tot * (1.0f / DM) + 1e-6f);
    float4 wv = ((const float4*)nw)[threadIdx.x];
    ((ushort4*)(d + (size_t)row * DM))[threadIdx.x] =
        make_ushort4(bf16u(v.x*ri*wv.x), bf16u(v.y*ri*wv.y),
                     bf16u(v.z*ri*wv.z), bf16u(v.w*ri*wv.w));
}

// ---------------- all weight casts in ONE dispatch ---------------------------
__device__ __forceinline__ void cast8(const float* __restrict__ s,
                                      ushort* __restrict__ d, int i)
{
    float4 a = ((const float4*)s)[2*i], b = ((const float4*)s)[2*i+1];
    ((ushort4*)d)[2*i]   = make_ushort4(bf16u(a.x), bf16u(a.y), bf16u(a.z), bf16u(a.w));
    ((ushort4*)d)[2*i+1] = make_ushort4(bf16u(b.x), bf16u(b.y), bf16u(b.z), bf16u(b.w));
}
__global__ __launch_bounds__(256) void k_castw(
    const float* __restrict__ s0, ushort* __restrict__ d0,
    const float* __restrict__ s1, ushort* __restrict__ d1,
    const float* __restrict__ s2, ushort* __restrict__ d2,
    const float* __restrict__ s3, ushort* __restrict__ d3)
{
    int i = blockIdx.x * 256 + threadIdx.x;
    if (i < 524288)       cast8(s0, d0, i);
    else if (i < 1048576) cast8(s1, d1, i - 524288);
    else if (i < 1064960) cast8(s2, d2, i - 1048576);
    else                  cast8(s3, d3, i - 1064960);
}

// ------- MFMA NT GEMM, BM templated (128 or 64) x 128, BK=64, swizzled -------
// MODE 0: bf16 out (C0b, row-major ldc).
// MODE 1: non-XP -> softplus dt TRANSPOSED bf16 into C0b[b][col][t];
//         XP -> f32 B TRANSPOSED into C1[b][n][t] (BssT).
// MODE 2: f32 out + skip (C0).
template<int MODE, int BM>
__global__ __launch_bounds__(256) void k_mfma(
    const ushort* __restrict__ Abf, const ushort* __restrict__ Bbf0,
    const ushort* __restrict__ Bbf1, float* __restrict__ C0,
    ushort* __restrict__ C0b, float* __restrict__ C1,
    const float* __restrict__ bias, const float* __restrict__ skip,
    int Kdim, int ldc)
{
    constexpr int NI = (BM == 128) ? 4 : 2;
    constexpr int SA = BM / 32;
    __shared__ __align__(16) ushort As[BM*64];
    __shared__ __align__(16) ushort Bs[128*64];
    const int t = threadIdx.x, w = t >> 6, lane = t & 63;
    const int nwg = gridDim.x * gridDim.y;
    const int orig = blockIdx.y * gridDim.x + blockIdx.x;
    const int swz = (orig & 7) * (nwg >> 3) + (orig >> 3);
    const int nt = swz % gridDim.x, mt = swz / gridDim.x;
    const int mBase = mt * BM, nBase = nt * 128;
    const bool isXP = (MODE == 1) && (nt == 16);
    const ushort* __restrict__ Bbf = isXP ? Bbf1 : Bbf0;
    const int wr = (BM == 128) ? (w >> 1) * 64 : 0;
    const int wc = (BM == 128) ? (w & 1) * 64 : w * 32;
    const int sR = lane >> 3;
    const int sK = ((lane & 7) ^ sR) * 8;

    f32x4 acc[4][NI];
    #pragma unroll
    for (int i = 0; i < 4; ++i)
        #pragma unroll
        for (int j = 0; j < NI; ++j)
            acc[i][j] = (f32x4){0.f, 0.f, 0.f, 0.f};

    for (int kt = 0; kt < Kdim; kt += 64) {
        #pragma unroll
        for (int s = 0; s < SA; ++s) {
            int tr = w*8 + s*32 + sR;
            gld16(Abf + (size_t)(mBase + tr) * Kdim + kt + sK,
                  As + (w*8 + s*32) * 64);
        }
        #pragma unroll
        for (int s = 0; s < 4; ++s) {
            int tr = w*8 + s*32 + sR;
            int gr = isXP ? (tr < 63 ? tr : 63) : (nBase + tr);
            gld16(Bbf + (size_t)gr * Kdim + kt + sK,
                  Bs + (w*8 + s*32) * 64);
        }
        __syncthreads();
        #pragma unroll
        for (int kk = 0; kk < 2; ++kk) {
            short8 af[4], bfr[NI];
            #pragma unroll
            for (int f = 0; f < 4; ++f) {
                int ra = wr + f*16 + (lane & 15);
                int ca = (kk*4 + (lane >> 4)) ^ (ra & 7);
                af[f] = *(const short8*)(As + ra*64 + ca*8);
            }
            #pragma unroll
            for (int f = 0; f < NI; ++f) {
                int rb2 = wc + f*16 + (lane & 15);
                int cb2 = (kk*4 + (lane >> 4)) ^ (rb2 & 7);
                bfr[f] = *(const short8*)(Bs + rb2*64 + cb2*8);
            }
            #pragma unroll
            for (int mi = 0; mi < 4; ++mi)
                #pragma unroll
                for (int ni = 0; ni < NI; ++ni)
                    acc[mi][ni] = __builtin_amdgcn_mfma_f32_16x16x32_bf16(
                        af[mi], bfr[ni], acc[mi][ni], 0, 0, 0);
        }
        __syncthreads();
    }

    const int rb = (lane >> 4) * 4, cbl = lane & 15;
    #pragma unroll
    for (int mi = 0; mi < 4; ++mi) {
        #pragma unroll
        for (int ni = 0; ni < NI; ++ni) {
            int ltcol = wc + ni*16 + cbl;
            int col = nBase + ltcol;
            int row0 = mBase + wr + mi*16 + rb;
            if constexpr (MODE == 0) {
                #pragma unroll
                for (int j = 0; j < 4; ++j)
                    C0b[(size_t)(row0+j) * ldc + col] = bf16u(acc[mi][ni][j]);
            } else if constexpr (MODE == 1) {
                int b_ = row0 >> 10, trow = row0 & 1023;
                if (isXP) {
                    if (ltcol < NS) {
                        f32x4 v = acc[mi][ni];
                        *(f32x4*)(C1 + ((size_t)b_ * NS + ltcol) * L_DIM + trow) = v;
                    }
                } else {
                    ushort o[4];
                    #pragma unroll
                    for (int j = 0; j < 4; ++j) {
                        float z = acc[mi][ni][j] + bias[col];
                        float sp = (z > 20.f) ? z : logf(1.f + expf(z));
                        o[j] = bf16u(sp);
                    }
                    *(ushort4*)(C0b + ((size_t)b_ * DI + col) * L_DIM + trow) =
                        *(ushort4*)o;
                }
            } else {
                #pragma unroll
                for (int j = 0; j < 4; ++j)
                    C0[(size_t)(row0+j) * ldc + col] =
                        acc[mi][ni][j] + skip[(size_t)(row0+j) * ldc + col];
            }
        }
    }
}

// ----- fused causal conv1d(K=4)+SiLU -> xc row-major AND xct transposed ------
__global__ __launch_bounds__(256) void k_convt(const ushort* __restrict__ xrb,
    const float* __restrict__ cw, const float* __restrict__ cb,
    ushort* __restrict__ xcb, ushort* __restrict__ xct)
{
    __shared__ __align__(16) ushort in[68][72];   // rows 0..66 = t0-3..t0+63
    __shared__ __align__(16) ushort ot[64][72];   // conv output, swizzled
    const int dt_ = blockIdx.x;                   // d tile (32)
    const int tt_ = blockIdx.y;                   // t tile (16)
    const int b   = blockIdx.z;
    const int d0 = dt_ * 64, t0 = tt_ * 64;
    const int tx = threadIdx.x & 7, ty = threadIdx.x >> 3;   // 8 x 32
    const ushort* src = xrb + (size_t)b * L_DIM * (2*DI) + d0;

    for (int r = threadIdx.x >> 3; r < 67; r += 32) {
        int tg = t0 - 3 + r;
        short8 v;
        if (tg < 0) {
            v = (short8){0,0,0,0,0,0,0,0};
        } else {
            v = *(const short8*)(src + (size_t)tg * (2*DI) + tx*8);
        }
        *(short8*)&in[r][tx*8] = v;
    }
    float wj[4][8];
    float bias8[8];
    #pragma unroll
    for (int j = 0; j < 8; ++j) {
        int dg = d0 + tx*8 + j;
        bias8[j] = cb[dg];
        #pragma unroll
        for (int c = 0; c < 4; ++c) wj[c][j] = cw[(size_t)dg * 4 + c];
    }
    __syncthreads();

    #pragma unroll
    for (int p = 0; p < 2; ++p) {
        int r = ty + p*32;                        // local t index
        short8 x0 = *(const short8*)&in[r + 0][tx*8];
        short8 x1 = *(const short8*)&in[r + 1][tx*8];
        short8 x2 = *(const short8*)&in[r + 2][tx*8];
        short8 x3 = *(const short8*)&in[r + 3][tx*8];
        ushort o[8];
        #pragma unroll
        for (int j = 0; j < 8; ++j) {
            float a = bias8[j];
            a = fmaf(wj[0][j], bf2f(((const ushort*)&x0)[j]), a);
            a = fmaf(wj[1][j], bf2f(((const ushort*)&x1)[j]), a);
            a = fmaf(wj[2][j], bf2f(((const ushort*)&x2)[j]), a);
            a = fmaf(wj[3][j], bf2f(((const ushort*)&x3)[j]), a);
            a = a / (1.f + expf(-a));
            o[j] = bf16u(a);
        }
        *(short8*)(xcb + ((size_t)(b * L_DIM + t0 + r) * DI) + d0 + tx*8) =
            *(short8*)o;
        int g = tx ^ ((r >> 3) & 7);
        *(short8*)&ot[r][g*8] = *(short8*)o;
    }
    __syncthreads();
    #pragma unroll
    for (int p = 0; p < 2; ++p) {
        int crow = ty + p*32;                     // d index within tile
        ushort o[8];
        #pragma unroll
        for (int j = 0; j < 8; ++j)
            o[j] = ot[tx*8 + j][(((crow >> 3) ^ tx) << 3) + (crow & 7)];
        *(short8*)(xct + ((size_t)b * DI + d0 + crow) * L_DIM + t0 + tx*8) =
            *(short8*)o;
    }
}

// ------ back-transpose yt[b][d][t](bf16) -> y_bf[b*t][d], fused silu gate ----
__global__ __launch_bounds__(256) void k_trg(const ushort* __restrict__ yt,
    const ushort* __restrict__ xrb, ushort* __restrict__ ybf)
{
    __shared__ __align__(16) ushort tile[64][72];
    const int r0 = blockIdx.y * 64, c0 = blockIdx.x * 64;  // r: d, c: t
    const int z = blockIdx.z;
    const ushort* s = yt + (size_t)z * DI * L_DIM;
    const int tx = threadIdx.x & 7, ty = threadIdx.x >> 3;
    #pragma unroll
    for (int p = 0; p < 2; ++p) {
        int r = ty + p*32;
        short8 v = *(const short8*)(s + (size_t)(r0 + r) * L_DIM + c0 + tx*8);
        int g = tx ^ ((r >> 3) & 7);
        *(short8*)&tile[r][g*8] = v;
    }
    __syncthreads();
    #pragma unroll
    for (int p = 0; p < 2; ++p) {
        int crow = ty + p*32;                 // t index within tile
        int row = z * L_DIM + c0 + crow;      // global (b*t) row
        ushort4 gu0 = *(const ushort4*)(xrb + (size_t)row * (2*DI) + DI + r0 + tx*8);
        ushort4 gu1 = *(const ushort4*)(xrb + (size_t)row * (2*DI) + DI + r0 + tx*8 + 4);
        ushort o[8];
        #pragma unroll
        for (int j = 0; j < 8; ++j) {
            float yv = bf2f(tile[tx*8 + j][(((crow >> 3) ^ tx) << 3) + (crow & 7)]);
            float g = bf2f(j < 4 ? ((const ushort*)&gu0)[j] : ((const ushort*)&gu1)[j-4]);
            o[j] = bf16u(yv * g / (1.f + expf(-g)));
        }
        *(short8*)(ybf + (size_t)row * DI + r0 + tx*8) = *(short8*)o;
    }
}

__device__ __forceinline__ float exp2_fast(float x)
{
    float r;
    asm("v_exp_f32 %0, %1" : "=v"(r) : "v"(x));
    return r;
}

// ---------------- selective scan v11: BshT[n][t] + b128 B-reads --------------
__global__ __launch_bounds__(256) void k_scan11(const ushort* __restrict__ dtt,
    const ushort* __restrict__ xct, const float* __restrict__ BssT,
    const float* __restrict__ A_log, const float* __restrict__ Dp,
    ushort* __restrict__ yt)
{
    __shared__ __align__(16) float BshT[64][68];
    __shared__ __align__(16) float Psh[4][64][8];
    __shared__ __align__(16) float Dsh[4][64];
    __shared__ __align__(16) float Xsh[4][64];
    const int lane = threadIdx.x & 63;
    const int widx = threadIdx.x >> 6;
    const int b = blockIdx.x >> 9;
    const int d = (blockIdx.x & 511) * 4 + widx;
    const float aL2 = -expf(A_log[(size_t)d * NS + lane]) * 1.44269504f;
    const float Dv = Dp[d];
    const ushort* dtp = dtt + ((size_t)b * DI + d) * L_DIM;
    const ushort* xcp = xct + ((size_t)b * DI + d) * L_DIM;
    const float* BpT = BssT + ((size_t)b * NS + lane) * L_DIM;
    ushort* yp = yt + ((size_t)b * DI + d) * L_DIM;
    const int pg = lane >> 3;
    const bool pwrite = (lane & 7) == 7;
    float h = 0.f;

    for (int t0 = 0; t0 < L_DIM; t0 += 64) {
        const float* bsrc = BpT + t0 + widx*16;
        float4 b0 = *(const float4*)(bsrc);
        float4 b1 = *(const float4*)(bsrc + 4);
        float4 b2 = *(const float4*)(bsrc + 8);
        float4 b3 = *(const float4*)(bsrc + 12);
        float dt_v = bf2f(dtp[t0 + lane]);
        float xc_v = bf2f(xcp[t0 + lane]);
        __syncthreads();
        *(float4*)&BshT[lane][widx*16]      = b0;
        *(float4*)&BshT[lane][widx*16 + 4]  = b1;
        *(float4*)&BshT[lane][widx*16 + 8]  = b2;
        *(float4*)&BshT[lane][widx*16 + 12] = b3;
        Dsh[widx][lane] = dt_v;
        Xsh[widx][lane] = xc_v;
        __syncthreads();
        #pragma unroll
        for (int q = 0; q < 64; q += 4) {
            float4 dt4 = *(const float4*)&Dsh[widx][q];
            float4 xc4 = *(const float4*)&Xsh[widx][q];
            float4 Bq  = *(const float4*)&BshT[lane][q];
            float s0, s1, s2, s3;
            {
                float p, ad;
                p  = xc4.x * Bq.x;
                ad = exp2_fast(aL2 * dt4.x);
                h = fmaf(ad, h, p); s0 = h;
                p  = xc4.y * Bq.y;
                ad = exp2_fast(aL2 * dt4.y);
                h = fmaf(ad, h, p); s1 = h;
                p  = xc4.z * Bq.z;
                ad = exp2_fast(aL2 * dt4.z);
                h = fmaf(ad, h, p); s2 = h;
                p  = xc4.w * Bq.w;
                ad = exp2_fast(aL2 * dt4.w);
                h = fmaf(ad, h, p); s3 = h;
            }
            asm("v_add_f32_dpp %0, %0, %0 row_shr:1 row_mask:0xf bank_mask:0xf\n\t"
                "v_add_f32_dpp %1, %1, %1 row_shr:1 row_mask:0xf bank_mask:0xf\n\t"
                "v_add_f32_dpp %2, %2, %2 row_shr:1 row_mask:0xf bank_mask:0xf\n\t"
                "v_add_f32_dpp %3, %3, %3 row_shr:1 row_mask:0xf bank_mask:0xf\n\t"
                "v_add_f32_dpp %0, %0, %0 row_shr:2 row_mask:0xf bank_mask:0xf\n\t"
                "v_add_f32_dpp %1, %1, %1 row_shr:2 row_mask:0xf bank_mask:0xf\n\t"
                "v_add_f32_dpp %2, %2, %2 row_shr:2 row_mask:0xf bank_mask:0xf\n\t"
                "v_add_f32_dpp %3, %3, %3 row_shr:2 row_mask:0xf bank_mask:0xf\n\t"
                "v_add_f32_dpp %0, %0, %0 row_shr:4 row_mask:0xf bank_mask:0xf\n\t"
                "v_add_f32_dpp %1, %1, %1 row_shr:4 row_mask:0xf bank_mask:0xf\n\t"
                "v_add_f32_dpp %2, %2, %2 row_shr:4 row_mask:0xf bank_mask:0xf\n\t"
                "v_add_f32_dpp %3, %3, %3 row_shr:4 row_mask:0xf bank_mask:0xf"
                : "+v"(s0), "+v"(s1), "+v"(s2), "+v"(s3));
            if (pwrite) {
                Psh[widx][q+0][pg] = s0;
                Psh[widx][q+1][pg] = s1;
                Psh[widx][q+2][pg] = s2;
                Psh[widx][q+3][pg] = s3;
            }
        }
        asm volatile("s_waitcnt lgkmcnt(0)" ::: "memory");
        __builtin_amdgcn_sched_barrier(0);
        float4 p0 = *(const float4*)&Psh[widx][lane][0];
        float4 p1 = *(const float4*)&Psh[widx][lane][4];
        float sum = ((p0.x + p0.y) + (p0.z + p0.w))
                  + ((p1.x + p1.y) + (p1.z + p1.w));
        yp[t0 + lane] = bf16u(fmaf(Dv, xc_v, sum));
    }
}

extern "C" void kernel_launch(void* const* d_in, const int* in_sizes, int n_in,
                              void* d_out, int out_size, void* d_ws, size_t ws_size,
                              hipStream_t stream)
{
    const float* x        = (const float*)d_in[0];
    const float* norm_w   = (const float*)d_in[1];
    const float* in_projw = (const float*)d_in[2];
    const float* conv_w   = (const float*)d_in[3];
    const float* conv_b   = (const float*)d_in[4];
    const float* x_projw  = (const float*)d_in[5];
    const float* dt_w     = (const float*)d_in[6];
    const float* dt_b     = (const float*)d_in[7];
    const float* A_log    = (const float*)d_in[8];
    const float* D_param  = (const float*)d_in[9];
    const float* out_projw= (const float*)d_in[10];
    float* out = (float*)d_out;

    ushort* wsu = (ushort*)d_ws;
    ushort* xr_bf  = wsu;                                   // 8M u16
    ushort* xc_bf  = xr_bf + (size_t)8*1024*1024;           // 4M u16
    ushort* dtb_bf = xc_bf + (size_t)4*1024*1024;           // 4M u16 (yt alias)
    ushort* dtt_bf = dtb_bf + (size_t)4*1024*1024;          // 4M u16
    ushort* xct_bf = dtt_bf + (size_t)4*1024*1024;          // 4M u16
    ushort* xn_bf  = xct_bf + (size_t)4*1024*1024;          // 2M u16
    ushort* xpw_bf = xn_bf + (size_t)2*1024*1024;           // 128K u16
    ushort* opw_bf = xpw_bf + 131072;                       // 2M u16
    float*  BssT   = (float*)(opw_bf + (size_t)2*1024*1024); // 128K f32 [b][n][t]
    ushort* dtw_bf = (ushort*)(BssT + 131072);              // fresh 4M u16
    // aliases into dead regions:
    ushort* inpw_bf = dtt_bf;     // consumed by GEMM0, before GEMM1 writes dtt
    ushort* y_bf    = xc_bf;      // xc dead after GEMM1 (xct is separate now)
    ushort* yt_bf   = dtb_bf;     // scratch for scan output

    k_castw<<<5184, 256, 0, stream>>>(in_projw, inpw_bf, dt_w, dtw_bf,
                                      x_projw + (size_t)64*2048, xpw_bf,
                                      out_projw, opw_bf);
    k_rms_xn<<<2048, 256, 0, stream>>>(x, norm_w, xn_bf);
    k_mfma<0,128><<<dim3(32, 16), 256, 0, stream>>>(xn_bf, inpw_bf, nullptr,
                                                nullptr, xr_bf, nullptr,
                                                nullptr, nullptr, 1024, 4096);
    // fused conv+SiLU -> xc (row-major) + xct (transposed)
    k_convt<<<dim3(32, 16, 2), 256, 0, stream>>>(xr_bf, conv_w, conv_b,
                                                 xc_bf, xct_bf);
    // GEMM1: dt transposed bf16 into dtt_bf[b][d][t]; B transposed f32 BssT
    k_mfma<1,128><<<dim3(17, 16), 256, 0, stream>>>(xc_bf, dtw_bf, xpw_bf,
                                                nullptr, dtt_bf, BssT,
                                                dt_b, nullptr, 2048, 2048);
    k_scan11<<<1024, 256, 0, stream>>>(dtt_bf, xct_bf, BssT, A_log, D_param, yt_bf);
    k_trg<<<dim3(16, 32, 2), 256, 0, stream>>>(yt_bf, xr_bf, y_bf);
    k_mfma<2,64><<<dim3(8, 32), 256, 0, stream>>>(y_bf, opw_bf, nullptr,
                                               out, nullptr, nullptr,
                                               nullptr, x, 2048, 1024);
}